// Round 1
// baseline (603.292 us; speedup 1.0000x reference)
//
#include <hip/hip_runtime.h>

namespace {
constexpr int GX = 200, GY = 200, GZ = 20;
constexpr int NVOX = GX * GY * GZ;            // 800000
constexpr float VMINX = -40.f, VMINY = -40.f, VMINZ = -4.f;
constexpr float VMAXX =  40.f, VMAXY =  40.f, VMAXZ =  4.f;
constexpr float VS    = 0.4f;                 // voxel size
constexpr float SIGF  = 3.0f;                 // sigma factor
}

// One wave (64 lanes) per Gaussian. All lanes redundantly compute the
// per-Gaussian setup (cheap, ~100 flops), then stride over the valid voxel
// window (dx*dy*dz <= 512, typically ~91) doing 9 hw float atomics each.
__global__ __launch_bounds__(256) void voxel_scatter(
    const float* __restrict__ means, const float* __restrict__ opacs,
    const float* __restrict__ scales, const float* __restrict__ rots,
    const float* __restrict__ feats, float* __restrict__ density,
    float* __restrict__ gfeat, int N)
{
    const int g    = (blockIdx.x * blockDim.x + threadIdx.x) >> 6;
    const int lane = threadIdx.x & 63;
    if (g >= N) return;

    const float op = opacs[g];
    const float mx = means[3*g+0], my = means[3*g+1], mz = means[3*g+2];
    const float sx = scales[3*g+0], sy = scales[3*g+1], sz = scales[3*g+2];
    const float q0 = rots[4*g+0], q1 = rots[4*g+1], q2 = rots[4*g+2], q3 = rots[4*g+3];

    // q = rot / sqrt(sum(rot^2) + 1e-8)
    const float qn = sqrtf(q0*q0 + q1*q1 + q2*q2 + q3*q3 + 1e-8f);
    const float r = q0/qn, x = q1/qn, y = q2/qn, z = q3/qn;

    const float R00 = 1.f - 2.f*(y*y + z*z), R01 = 2.f*(x*y - r*z), R02 = 2.f*(x*z + r*y);
    const float R10 = 2.f*(x*y + r*z), R11 = 1.f - 2.f*(x*x + z*z), R12 = 2.f*(y*z - r*x);
    const float R20 = 2.f*(x*z - r*y), R21 = 2.f*(y*z + r*x), R22 = 1.f - 2.f*(x*x + y*y);

    // cov = R diag(s^2) R^T (symmetric)
    const float s0 = sx*sx, s1 = sy*sy, s2 = sz*sz;
    const float c00 = R00*R00*s0 + R01*R01*s1 + R02*R02*s2;
    const float c01 = R00*R10*s0 + R01*R11*s1 + R02*R12*s2;
    const float c02 = R00*R20*s0 + R01*R21*s1 + R02*R22*s2;
    const float c11 = R10*R10*s0 + R11*R11*s1 + R12*R12*s2;
    const float c12 = R10*R20*s0 + R11*R21*s1 + R12*R22*s2;
    const float c22 = R20*R20*s0 + R21*R21*s1 + R22*R22*s2;

    const float sgx = SIGF * sqrtf(c00), sgy = SIGF * sqrtf(c11), sgz = SIGF * sqrtf(c22);
    const float bminx = mx - sgx, bminy = my - sgy, bminz = mz - sgz;
    const float bmaxx = mx + sgx, bmaxy = my + sgy, bmaxz = mz + sgz;

    // keep mask: removed Gaussians contribute exact zeros in the reference,
    // so skipping the whole wave is identical.
    const bool keep = (bmaxx > VMINX) && (bmaxy > VMINY) && (bmaxz > VMINZ)
                   && (bminx < VMAXX) && (bminy < VMAXY) && (bminz < VMAXZ)
                   && (op > 1e-4f);
    if (!keep) return;

    // trunc-toward-zero cast matches astype(int32)
    const int ix0 = max((int)((bminx - VMINX) / VS), 0);
    const int iy0 = max((int)((bminy - VMINY) / VS), 0);
    const int iz0 = max((int)((bminz - VMINZ) / VS), 0);
    const int ix1 = min((int)((bmaxx - VMINX) / VS), GX - 1);
    const int iy1 = min((int)((bmaxy - VMINY) / VS), GY - 1);
    const int iz1 = min((int)((bmaxz - VMINZ) / VS), GZ - 1);

    // reference only enumerates offsets 0..7 from idx_min
    const int dx = min(ix1 - ix0 + 1, 8);
    const int dy = min(iy1 - iy0 + 1, 8);
    const int dz = min(iz1 - iz0 + 1, 8);
    if (dx <= 0 || dy <= 0 || dz <= 0) return;

    // analytic inverse of symmetric 3x3
    const float m00 = c11*c22 - c12*c12;
    const float m01 = c02*c12 - c01*c22;
    const float m02 = c01*c12 - c02*c11;
    const float det = c00*m00 + c01*m01 + c02*m02;
    const float id  = 1.f / det;
    const float i00 = m00*id, i01 = m01*id, i02 = m02*id;
    const float i11 = (c00*c22 - c02*c02)*id;
    const float i12 = (c01*c02 - c00*c12)*id;
    const float i22 = (c00*c11 - c01*c01)*id;

    const float4 f0 = *(const float4*)(feats + 8*g);
    const float4 f1 = *(const float4*)(feats + 8*g + 4);

    const int cnt = dx * dy * dz;
    for (int i = lane; i < cnt; i += 64) {
        const int oz = i % dz;
        const int t  = i / dz;
        const int oy = t % dy;
        const int ox = t / dy;
        const int vx = ix0 + ox, vy = iy0 + oy, vz = iz0 + oz;
        const float cx = (float)vx * VS + VMINX + 0.5f * VS;
        const float cy = (float)vy * VS + VMINY + 0.5f * VS;
        const float cz = (float)vz * VS + VMINZ + 0.5f * VS;
        const float ddx = cx - mx, ddy = cy - my, ddz = cz - mz;
        const float maha = i00*ddx*ddx + i11*ddy*ddy + i22*ddz*ddz
                         + 2.f*(i01*ddx*ddy + i02*ddx*ddz + i12*ddy*ddz);
        const float w = op * expf(-0.5f * maha);
        const int flat = (vx * GY + vy) * GZ + vz;
        unsafeAtomicAdd(density + flat, w);
        float* fb = gfeat + (size_t)flat * 8;
        unsafeAtomicAdd(fb + 0, w * f0.x);
        unsafeAtomicAdd(fb + 1, w * f0.y);
        unsafeAtomicAdd(fb + 2, w * f0.z);
        unsafeAtomicAdd(fb + 3, w * f0.w);
        unsafeAtomicAdd(fb + 4, w * f1.x);
        unsafeAtomicAdd(fb + 5, w * f1.y);
        unsafeAtomicAdd(fb + 6, w * f1.z);
        unsafeAtomicAdd(fb + 7, w * f1.w);
    }
}

__global__ __launch_bounds__(256) void voxel_norm(
    const float* __restrict__ density, float4* __restrict__ gfeat4)
{
    const int v = blockIdx.x * blockDim.x + threadIdx.x;
    if (v >= NVOX) return;
    const float inv = 1.f / fmaxf(density[v], 1e-6f);
    float4 a = gfeat4[2*v + 0];
    float4 b = gfeat4[2*v + 1];
    a.x *= inv; a.y *= inv; a.z *= inv; a.w *= inv;
    b.x *= inv; b.y *= inv; b.z *= inv; b.w *= inv;
    gfeat4[2*v + 0] = a;
    gfeat4[2*v + 1] = b;
}

extern "C" void kernel_launch(void* const* d_in, const int* in_sizes, int n_in,
                              void* d_out, int out_size, void* d_ws, size_t ws_size,
                              hipStream_t stream)
{
    const float* means  = (const float*)d_in[0];
    const float* opacs  = (const float*)d_in[1];
    const float* scales = (const float*)d_in[2];
    const float* rots   = (const float*)d_in[3];
    const float* feats  = (const float*)d_in[4];

    float* density = (float*)d_out;           // [V]
    float* gfeat   = density + NVOX;          // [V, 8]
    const int N = in_sizes[0] / 3;            // means3d is [B, N, 3], B=1

    // harness poisons d_out with 0xAA before every timed call
    hipMemsetAsync(d_out, 0, (size_t)out_size * sizeof(float), stream);

    const int blocks = (N * 64 + 255) / 256;  // one wave per Gaussian
    voxel_scatter<<<blocks, 256, 0, stream>>>(means, opacs, scales, rots, feats,
                                              density, gfeat, N);
    voxel_norm<<<(NVOX + 255) / 256, 256, 0, stream>>>(density, (float4*)gfeat);
}

// Round 2
// 129.855 us; speedup vs baseline: 4.6459x; 4.6459x over previous
//
#include <hip/hip_runtime.h>

namespace {
constexpr int GX = 200, GY = 200, GZ = 20;
constexpr int NVOX = GX * GY * GZ;            // 800000
constexpr float VMINX = -40.f, VMINY = -40.f, VMINZ = -4.f;
constexpr float VMAXX =  40.f, VMAXY =  40.f, VMAXZ =  4.f;
constexpr float VS    = 0.4f;                 // voxel size
constexpr float HVS   = 0.2f;                 // 0.5 * voxel size
constexpr float SIGF  = 3.0f;                 // sigma factor

constexpr int TILE   = 8;                     // tile is 8x8 in x,y; full z column
constexpr int TX     = GX / TILE;             // 25
constexpr int TY     = GY / TILE;             // 25
constexpr int NTILES = TX * TY;               // 625
constexpr int CAP    = 256;                   // max gaussians per tile list
}

// Shared per-Gaussian setup: covariance from quat+scales, analytic inverse,
// voxel window (trunc-toward-zero casts + clamps + 8-offset cap, matching ref).
// Returns false if the Gaussian is culled.
__device__ __forceinline__ bool gauss_setup(
    const float* __restrict__ means, const float* __restrict__ opacs,
    const float* __restrict__ scales, const float* __restrict__ rots,
    int g,
    int& gx0, int& gx1, int& gy0, int& gy1, int& gz0, int& gz1,
    float& i00, float& i01, float& i02, float& i11, float& i12, float& i22,
    float& mx, float& my, float& mz, float& op)
{
    op = opacs[g];
    mx = means[3*g+0]; my = means[3*g+1]; mz = means[3*g+2];
    const float sx = scales[3*g+0], sy = scales[3*g+1], sz = scales[3*g+2];
    const float q0 = rots[4*g+0], q1 = rots[4*g+1], q2 = rots[4*g+2], q3 = rots[4*g+3];

    const float qn = sqrtf(q0*q0 + q1*q1 + q2*q2 + q3*q3 + 1e-8f);
    const float r = q0/qn, x = q1/qn, y = q2/qn, z = q3/qn;

    const float R00 = 1.f - 2.f*(y*y + z*z), R01 = 2.f*(x*y - r*z), R02 = 2.f*(x*z + r*y);
    const float R10 = 2.f*(x*y + r*z), R11 = 1.f - 2.f*(x*x + z*z), R12 = 2.f*(y*z - r*x);
    const float R20 = 2.f*(x*z - r*y), R21 = 2.f*(y*z + r*x), R22 = 1.f - 2.f*(x*x + y*y);

    const float s0 = sx*sx, s1 = sy*sy, s2 = sz*sz;
    const float c00 = R00*R00*s0 + R01*R01*s1 + R02*R02*s2;
    const float c01 = R00*R10*s0 + R01*R11*s1 + R02*R12*s2;
    const float c02 = R00*R20*s0 + R01*R21*s1 + R02*R22*s2;
    const float c11 = R10*R10*s0 + R11*R11*s1 + R12*R12*s2;
    const float c12 = R10*R20*s0 + R11*R21*s1 + R12*R22*s2;
    const float c22 = R20*R20*s0 + R21*R21*s1 + R22*R22*s2;

    const float sgx = SIGF * sqrtf(c00), sgy = SIGF * sqrtf(c11), sgz = SIGF * sqrtf(c22);
    const float bminx = mx - sgx, bminy = my - sgy, bminz = mz - sgz;
    const float bmaxx = mx + sgx, bmaxy = my + sgy, bmaxz = mz + sgz;

    const bool keep = (bmaxx > VMINX) && (bmaxy > VMINY) && (bmaxz > VMINZ)
                   && (bminx < VMAXX) && (bminy < VMAXY) && (bminz < VMAXZ)
                   && (op > 1e-4f);
    if (!keep) return false;

    gx0 = max((int)((bminx - VMINX) / VS), 0);
    gy0 = max((int)((bminy - VMINY) / VS), 0);
    gz0 = max((int)((bminz - VMINZ) / VS), 0);
    gx1 = min((int)((bmaxx - VMINX) / VS), GX - 1);
    gy1 = min((int)((bmaxy - VMINY) / VS), GY - 1);
    gz1 = min((int)((bmaxz - VMINZ) / VS), GZ - 1);
    // reference enumerates only offsets 0..7 from idx_min
    gx1 = min(gx1, gx0 + 7);
    gy1 = min(gy1, gy0 + 7);
    gz1 = min(gz1, gz0 + 7);
    if (gx1 < gx0 || gy1 < gy0 || gz1 < gz0) return false;

    // analytic inverse of symmetric 3x3
    const float m00 = c11*c22 - c12*c12;
    const float m01 = c02*c12 - c01*c22;
    const float m02 = c01*c12 - c02*c11;
    const float det = c00*m00 + c01*m01 + c02*m02;
    const float id  = 1.f / det;
    i00 = m00*id; i01 = m01*id; i02 = m02*id;
    i11 = (c00*c22 - c02*c02)*id;
    i12 = (c01*c02 - c00*c12)*id;
    i22 = (c00*c11 - c01*c01)*id;
    return true;
}

// One thread per Gaussian: append id to each touched tile's list (<=2x2 tiles).
__global__ __launch_bounds__(256) void voxel_bin(
    const float* __restrict__ means, const float* __restrict__ opacs,
    const float* __restrict__ scales, const float* __restrict__ rots,
    int* __restrict__ counts, int* __restrict__ entries, int N)
{
    const int g = blockIdx.x * blockDim.x + threadIdx.x;
    if (g >= N) return;
    int gx0, gx1, gy0, gy1, gz0, gz1;
    float i00,i01,i02,i11,i12,i22, mx,my,mz, op;
    if (!gauss_setup(means, opacs, scales, rots, g,
                     gx0,gx1,gy0,gy1,gz0,gz1, i00,i01,i02,i11,i12,i22, mx,my,mz, op))
        return;
    const int tx0 = gx0 >> 3, tx1 = gx1 >> 3;
    const int ty0 = gy0 >> 3, ty1 = gy1 >> 3;
    for (int tx = tx0; tx <= tx1; ++tx)
        for (int ty = ty0; ty <= ty1; ++ty) {
            const int t = tx * TY + ty;
            const int slot = atomicAdd(&counts[t], 1);
            if (slot < CAP) entries[t * CAP + slot] = g;
        }
}

// One 256-thread block per tile. Stage gaussian params in LDS, each thread
// accumulates a 5-voxel z-column segment in registers, writes once (norm fused).
__global__ __launch_bounds__(256) void voxel_gather(
    const float* __restrict__ means, const float* __restrict__ opacs,
    const float* __restrict__ scales, const float* __restrict__ rots,
    const float* __restrict__ feats,
    const int* __restrict__ counts, const int* __restrict__ entries,
    float* __restrict__ density, float* __restrict__ gfeat)
{
    __shared__ float gs[CAP][20];   // [i00..i22, mx,my,mz, op, f0..f7, win0, win1]

    const int tile = blockIdx.x;
    const int ttx = tile / TY, tty = tile % TY;
    const int tid = threadIdx.x;
    const int cnt = min(counts[tile], CAP);

    if (tid < cnt) {
        const int g = entries[tile * CAP + tid];
        int gx0, gx1, gy0, gy1, gz0, gz1;
        float i00,i01,i02,i11,i12,i22, mx,my,mz, op;
        gauss_setup(means, opacs, scales, rots, g,
                    gx0,gx1,gy0,gy1,gz0,gz1, i00,i01,i02,i11,i12,i22, mx,my,mz, op);
        float* G = gs[tid];
        G[0]=i00; G[1]=i01; G[2]=i02; G[3]=i11; G[4]=i12; G[5]=i22;
        G[6]=mx; G[7]=my; G[8]=mz; G[9]=op;
        const float4 f0 = *(const float4*)(feats + 8*g);
        const float4 f1 = *(const float4*)(feats + 8*g + 4);
        G[10]=f0.x; G[11]=f0.y; G[12]=f0.z; G[13]=f0.w;
        G[14]=f1.x; G[15]=f1.y; G[16]=f1.z; G[17]=f1.w;
        G[18] = __int_as_float(gx0 | (gy0<<8) | (gz0<<16));
        G[19] = __int_as_float(gx1 | (gy1<<8) | (gz1<<16));
    }
    __syncthreads();

    const int lx = tid & 7, ly = (tid >> 3) & 7, zs = (tid >> 6) * 5;
    const int vx = ttx * TILE + lx, vy = tty * TILE + ly;
    const float cx = (float)vx * VS + VMINX + HVS;
    const float cy = (float)vy * VS + VMINY + HVS;

    float den[5] = {0.f, 0.f, 0.f, 0.f, 0.f};
    float ft[5][8] = {};

    for (int j = 0; j < cnt; ++j) {
        const float* G = gs[j];
        const int w0 = __float_as_int(G[18]);
        const int w1 = __float_as_int(G[19]);
        const int gx0 = w0 & 255, gy0 = (w0 >> 8) & 255, gz0 = (w0 >> 16) & 255;
        const int gx1 = w1 & 255, gy1 = (w1 >> 8) & 255, gz1 = (w1 >> 16) & 255;
        if (vx < gx0 || vx > gx1 || vy < gy0 || vy > gy1) continue;

        const float ddx = cx - G[6], ddy = cy - G[7];
        const float i00 = G[0], i01 = G[1], i02 = G[2];
        const float i11 = G[3], i12 = G[4], i22 = G[5];
        const float base = i00*ddx*ddx + 2.f*i01*ddx*ddy + i11*ddy*ddy;
        const float bz   = 2.f*(i02*ddx + i12*ddy);
        const float mz = G[8], op = G[9];
        const float f[8] = {G[10],G[11],G[12],G[13],G[14],G[15],G[16],G[17]};

        #pragma unroll
        for (int k = 0; k < 5; ++k) {
            const int vz = zs + k;
            if (vz < gz0 || vz > gz1) continue;
            const float ddz = ((float)vz * VS + VMINZ + HVS) - mz;
            const float w = op * __expf(-0.5f * (base + ddz * (bz + i22 * ddz)));
            den[k] += w;
            #pragma unroll
            for (int c = 0; c < 8; ++c) ft[k][c] += w * f[c];
        }
    }

    #pragma unroll
    for (int k = 0; k < 5; ++k) {
        const int vz = zs + k;
        const int flat = (vx * GY + vy) * GZ + vz;
        density[flat] = den[k];
        const float inv = 1.f / fmaxf(den[k], 1e-6f);
        float4 a = make_float4(ft[k][0]*inv, ft[k][1]*inv, ft[k][2]*inv, ft[k][3]*inv);
        float4 b = make_float4(ft[k][4]*inv, ft[k][5]*inv, ft[k][6]*inv, ft[k][7]*inv);
        *(float4*)(gfeat + (size_t)flat * 8)     = a;
        *(float4*)(gfeat + (size_t)flat * 8 + 4) = b;
    }
}

extern "C" void kernel_launch(void* const* d_in, const int* in_sizes, int n_in,
                              void* d_out, int out_size, void* d_ws, size_t ws_size,
                              hipStream_t stream)
{
    const float* means  = (const float*)d_in[0];
    const float* opacs  = (const float*)d_in[1];
    const float* scales = (const float*)d_in[2];
    const float* rots   = (const float*)d_in[3];
    const float* feats  = (const float*)d_in[4];

    float* density = (float*)d_out;           // [V]
    float* gfeat   = density + NVOX;          // [V, 8]
    const int N = in_sizes[0] / 3;            // means3d is [B, N, 3], B=1

    int* counts  = (int*)d_ws;                // [625]
    int* entries = counts + 640;              // [625 * 256]

    // ws is poisoned 0xAA before every timed call; zero the tile counters
    hipMemsetAsync(counts, 0, NTILES * sizeof(int), stream);

    voxel_bin<<<(N + 255) / 256, 256, 0, stream>>>(means, opacs, scales, rots,
                                                   counts, entries, N);
    voxel_gather<<<NTILES, 256, 0, stream>>>(means, opacs, scales, rots, feats,
                                             counts, entries, density, gfeat);
}